// Round 1
// baseline (462.007 us; speedup 1.0000x reference)
//
#include <hip/hip_runtime.h>
#include <cstdint>
#include <cstddef>

#define HID 128
#define SEQL 28
#define INP 28
#define NL 10
#define NC 10
#define BATCH 4096
#define BB 16          // batch rows per block
#define KP 264         // padded K (256 + 8 halfs -> bank-conflict-free b128)

typedef _Float16 half8 __attribute__((ext_vector_type(8)));
typedef float    f32x4 __attribute__((ext_vector_type(4)));

// ---------------- ws layout (bytes) ----------------
// Wcat : [NL][HID][256] f16  : 655360 @ 0
//        layer 0 row n: [Wih0[n][0:28] | 0 x4 | Whh0[n][0:128] | 0 x96]
//        layer l row n: [Wih[l-1][n][0:128] | Whh[l][n][0:128]]
// bias : [NL][HID] f32       : 5120   @ 655360   (b_ih + b_hh)
// seq  : [BATCH][SEQL][HID] f16 : 29360128 @ 660480 (inter-layer acts, in-place)
#define WS_WCAT_OFF 0
#define WS_BIAS_OFF 655360
#define WS_SEQ_OFF  660480

__global__ void convert_weights(const float* __restrict__ Wih0,
                                const float* __restrict__ Wih,
                                const float* __restrict__ Whh,
                                const float* __restrict__ bih,
                                const float* __restrict__ bhh,
                                _Float16* __restrict__ Wcat,
                                float* __restrict__ bias) {
  int r = blockIdx.x * blockDim.x + threadIdx.x;
  if (r >= NL * HID) return;
  int l = r / HID, n = r % HID;
  _Float16* dst = Wcat + (size_t)r * 256;
  if (l == 0) {
    for (int k = 0; k < 256; ++k) {
      float v = 0.f;
      if (k < INP) v = Wih0[n * INP + k];
      else if (k >= 32 && k < 160) v = Whh[(size_t)n * HID + (k - 32)];
      dst[k] = (_Float16)v;
    }
  } else {
    for (int k = 0; k < HID; ++k)
      dst[k] = (_Float16)Wih[((size_t)(l - 1) * HID + n) * HID + k];
    for (int k = 0; k < HID; ++k)
      dst[HID + k] = (_Float16)Whh[((size_t)l * HID + n) * HID + k];
  }
  bias[r] = bih[r] + bhh[r];
}

__device__ __forceinline__ float tanh_fast(float v) {
  // 1 - 2/(e^{2v}+1); saturates correctly for |v| large (exp -> inf or 0)
  float e = __expf(2.f * v);
  return 1.f - 2.f / (e + 1.f);
}

__global__ __launch_bounds__(256) void rnn_fused(
    const float* __restrict__ x,
    const _Float16* __restrict__ Wcat,
    const float* __restrict__ bias,
    const float* __restrict__ fcW,
    const float* __restrict__ fcb,
    _Float16* __restrict__ seq,
    float* __restrict__ out) {
  // Activation panel: row m (batch), K columns [x_t | h] padded to KP
  __shared__ _Float16 Xc[BB * KP] __attribute__((aligned(16)));

  const int tid    = threadIdx.x;
  const int lane15 = tid & 15;        // MFMA: A-row m / B-col n / D-col n
  const int quad   = (tid >> 4) & 3;  // MFMA quad within wave
  const int wid    = tid >> 6;        // wave id 0..3 -> n range [wid*32, wid*32+32)
  const int b0     = blockIdx.x * BB;
  const int mrow   = tid >> 4;        // fill mapping: 16 rows x 16 segs
  const int kseg   = tid & 15;

  half8 bfrag[2][8];

  for (int l = 0; l < NL; ++l) {
    __syncthreads();  // previous layer fully done before reinit

    // --- stage B fragments (weights) into registers for this layer ---
    const _Float16* Wl = Wcat + (size_t)l * HID * 256;
#pragma unroll
    for (int nt = 0; nt < 2; ++nt) {
      int n = wid * 32 + nt * 16 + lane15;
#pragma unroll
      for (int ks = 0; ks < 8; ++ks)
        bfrag[nt][ks] = *(const half8*)(Wl + (size_t)n * 256 + ks * 32 + quad * 8);
    }
    const float bias0 = bias[l * HID + wid * 32 + lane15];
    const float bias1 = bias[l * HID + wid * 32 + 16 + lane15];

    // --- zero the panel (h := 0, plus K padding) ---
    {
      uint4 z4 = {0u, 0u, 0u, 0u};
      for (int i = tid; i < BB * KP / 8; i += 256) ((uint4*)Xc)[i] = z4;
    }
    __syncthreads();

    const int hoff = (l == 0) ? 32 : HID;  // where h lives in K

    for (int t = 0; t < SEQL; ++t) {
      // --- fill x_t part of panel ---
      if (l == 0) {
        const float* xb = x + ((size_t)(b0 + mrow) * SEQL + t) * INP;
        int c0 = kseg * 2, c1 = c0 + 1;
        Xc[mrow * KP + c0] = (_Float16)((c0 < INP) ? xb[c0] : 0.f);
        Xc[mrow * KP + c1] = (_Float16)((c1 < INP) ? xb[c1] : 0.f);
      } else {
        *(uint4*)(Xc + mrow * KP + kseg * 8) =
            *(const uint4*)(seq + ((size_t)(b0 + mrow) * SEQL + t) * HID + kseg * 8);
      }
      __syncthreads();  // panel (x and h) complete before reads

      // --- fused GEMM: D = [x|h] @ [Wih;Whh]^T + bias ---
      f32x4 acc0 = {bias0, bias0, bias0, bias0};
      f32x4 acc1 = {bias1, bias1, bias1, bias1};
#pragma unroll
      for (int ks = 0; ks < 8; ++ks) {
        half8 a = *(const half8*)(Xc + lane15 * KP + ks * 32 + quad * 8);
        acc0 = __builtin_amdgcn_mfma_f32_16x16x32_f16(a, bfrag[0][ks], acc0, 0, 0, 0);
        acc1 = __builtin_amdgcn_mfma_f32_16x16x32_f16(a, bfrag[1][ks], acc1, 0, 0, 0);
      }
      __syncthreads();  // all reads of panel done before h overwrite

      // --- tanh epilogue: write h into panel (LDS) and seq (global) ---
#pragma unroll
      for (int r = 0; r < 4; ++r) {
        int m = quad * 4 + r;                 // D row = m (batch row)
        int n0 = wid * 32 + lane15;           // D col = n (hidden unit)
        int n1 = n0 + 16;
        float v0 = tanh_fast(acc0[r]);
        float v1 = tanh_fast(acc1[r]);
        Xc[m * KP + hoff + n0] = (_Float16)v0;
        Xc[m * KP + hoff + n1] = (_Float16)v1;
        if (l < NL - 1) {
          _Float16* sp = seq + ((size_t)(b0 + m) * SEQL + t) * HID;
          sp[n0] = (_Float16)v0;
          sp[n1] = (_Float16)v1;
        }
      }
    }
  }
  __syncthreads();

  // --- FC on last hidden state (layer 9, t=27, sitting in Xc h-region) ---
  if (tid < BB * NC) {
    int c = tid >> 4;   // class 0..9
    int b = tid & 15;   // batch row within block
    float acc = fcb[c];
    const float* wr = fcW + c * HID;
    const _Float16* hr = Xc + b * KP + HID;
#pragma unroll 4
    for (int k = 0; k < HID; ++k) acc += (float)hr[k] * wr[k];
    out[(size_t)(b0 + b) * NC + c] = acc;
  }
}

extern "C" void kernel_launch(void* const* d_in, const int* in_sizes, int n_in,
                              void* d_out, int out_size, void* d_ws, size_t ws_size,
                              hipStream_t stream) {
  const float* x    = (const float*)d_in[0];
  const float* Wih0 = (const float*)d_in[1];
  const float* Wih  = (const float*)d_in[2];
  const float* Whh  = (const float*)d_in[3];
  const float* bih  = (const float*)d_in[4];
  const float* bhh  = (const float*)d_in[5];
  const float* fcW  = (const float*)d_in[6];
  const float* fcb  = (const float*)d_in[7];
  float* out = (float*)d_out;

  _Float16* Wcat = (_Float16*)((char*)d_ws + WS_WCAT_OFF);
  float*    bs   = (float*)((char*)d_ws + WS_BIAS_OFF);
  _Float16* seq  = (_Float16*)((char*)d_ws + WS_SEQ_OFF);

  convert_weights<<<dim3(5), dim3(256), 0, stream>>>(Wih0, Wih, Whh, bih, bhh, Wcat, bs);
  rnn_fused<<<dim3(BATCH / BB), dim3(256), 0, stream>>>(x, Wcat, bs, fcW, fcb, seq, out);
}

// Round 2
// 324.509 us; speedup vs baseline: 1.4237x; 1.4237x over previous
//
#include <hip/hip_runtime.h>
#include <cstdint>
#include <cstddef>

#define HID 128
#define SEQL 28
#define INP 28
#define NL 10
#define NC 10
#define BATCH 4096
#define BB 16          // batch rows per block
#define STRD 136       // padded row stride in halfs (272 B = 17*16, b128-aligned)
#define BUFH (16 * STRD)  // halfs per 16x128 activation buffer

typedef _Float16 half8 __attribute__((ext_vector_type(8)));
typedef float    f32x4 __attribute__((ext_vector_type(4)));

// ---------------- ws layout (bytes) ----------------
// Wcat : [NL][HID][256] f16 : 655360 @ 0
//        every layer row n: [Wih(128, layer0: x 28 zero-padded to 128) | Whh(128)]
// bias : [NL][HID] f32      : 5120   @ 655360   (b_ih + b_hh)
// seq  : [BATCH][SEQL][HID] f16 : 29360128 @ 660480 (group 0->1 boundary acts)
#define WS_WCAT_OFF 0
#define WS_BIAS_OFF 655360
#define WS_SEQ_OFF  660480

__global__ void convert_weights(const float* __restrict__ Wih0,
                                const float* __restrict__ Wih,
                                const float* __restrict__ Whh,
                                const float* __restrict__ bih,
                                const float* __restrict__ bhh,
                                _Float16* __restrict__ Wcat,
                                float* __restrict__ bias) {
  int tg = blockIdx.x * blockDim.x + threadIdx.x;
  if (tg >= NL * HID * 16) return;
  int r = tg >> 4, seg = tg & 15;     // 16 threads per output row
  int l = r / HID, n = r % HID;
  int k0 = seg * 16;                  // 16 halfs per thread; never straddles 128
  _Float16* dst = Wcat + (size_t)r * 256 + k0;
  if (l == 0) {
#pragma unroll
    for (int i = 0; i < 16; ++i) {
      int k = k0 + i;
      float v = 0.f;
      if (k < INP) v = Wih0[n * INP + k];
      else if (k >= HID) v = Whh[(size_t)n * HID + (k - HID)];
      dst[i] = (_Float16)v;
    }
  } else {
    const float* src = (k0 < HID)
        ? (Wih + ((size_t)(l - 1) * HID + n) * HID + k0)
        : (Whh + ((size_t)l * HID + n) * HID + (k0 - HID));
#pragma unroll
    for (int i = 0; i < 16; ++i) dst[i] = (_Float16)src[i];
  }
  if (seg == 0) bias[r] = bih[r] + bhh[r];
}

__device__ __forceinline__ float tanh_fast(float v) {
  float e = __expf(2.f * v);
  return 1.f - 2.f / (e + 1.f);
}

// LDS: X (group input at current t) + O[l][parity] for 5 layers.
// O(l,p) holds layer (g*5+l)'s output: read as h at t+1 and as input of l+1 at t.
__global__ __launch_bounds__(256, 1) void rnn_fused(
    const float* __restrict__ x,
    const _Float16* __restrict__ Wcat,
    const float* __restrict__ bias,
    const float* __restrict__ fcW,
    const float* __restrict__ fcb,
    _Float16* __restrict__ seq,
    float* __restrict__ out) {
  __shared__ _Float16 lds[BUFH * 11] __attribute__((aligned(16)));
  // X at lds+0 ; O(l,p) at lds + BUFH*(1 + 2*l + p)

  const int tid    = threadIdx.x;
  const int lane15 = tid & 15;        // MFMA A-row m / D-col n
  const int quad   = (tid >> 4) & 3;  // MFMA quad
  const int wid    = tid >> 6;        // wave id: n tiles [wid*32, wid*32+32)
  const int b0     = blockIdx.x * BB;
  const int mrow   = tid >> 4;        // fill mapping: 16 rows x 16 segs
  const int kseg   = tid & 15;

  half8 bfrag[5][2][8];
  float biasv[5][2];

  for (int g = 0; g < 2; ++g) {
    // --- stage 5 layers of weights into registers (≈320 VGPRs) ---
#pragma unroll
    for (int l = 0; l < 5; ++l) {
      const _Float16* Wl = Wcat + (size_t)(g * 5 + l) * HID * 256;
#pragma unroll
      for (int nt = 0; nt < 2; ++nt) {
        int n = wid * 32 + nt * 16 + lane15;
#pragma unroll
        for (int ks = 0; ks < 8; ++ks)
          bfrag[l][nt][ks] = *(const half8*)(Wl + (size_t)n * 256 + ks * 32 + quad * 8);
        biasv[l][nt] = bias[(g * 5 + l) * HID + n];
      }
    }
    __syncthreads();  // prev group's O reads complete before re-zeroing
    {                 // zero all O buffers (h=0 at t=0 reads parity 1)
      uint4 z; z.x = z.y = z.z = z.w = 0u;
      for (int i = tid; i < (BUFH * 10) / 8; i += 256)
        ((uint4*)(lds + BUFH))[i] = z;
    }   // completion covered by the (t=0, l=0) barrier below

    auto step = [&](int t, int pt) {
      // --- fill X = group input at time t ---
      if (g == 0) {
        const float* xb = x + ((size_t)(b0 + mrow) * SEQL + t) * INP;
        _Float16* xr = lds + mrow * STRD + kseg * 8;
#pragma unroll
        for (int i = 0; i < 8; ++i) {
          int c = kseg * 8 + i;
          xr[i] = (_Float16)((c < INP) ? xb[c] : 0.f);
        }
      } else {
        *(uint4*)(lds + mrow * STRD + kseg * 8) =
            *(const uint4*)(seq + ((size_t)(b0 + mrow) * SEQL + t) * HID + kseg * 8);
      }
#pragma unroll
      for (int l = 0; l < 5; ++l) {
        __syncthreads();  // inputs (X / O[l-1][pt]) complete; old reads done
        const _Float16* INb = (l == 0) ? lds : lds + BUFH * (1 + 2 * (l - 1) + pt);
        const _Float16* Hb  = lds + BUFH * (1 + 2 * l + (1 - pt));
        _Float16*       Ob  = lds + BUFH * (1 + 2 * l + pt);

        f32x4 acc0 = {biasv[l][0], biasv[l][0], biasv[l][0], biasv[l][0]};
        f32x4 acc1 = {biasv[l][1], biasv[l][1], biasv[l][1], biasv[l][1]};
#pragma unroll
        for (int ks = 0; ks < 4; ++ks) {
          half8 a = *(const half8*)(INb + lane15 * STRD + ks * 32 + quad * 8);
          acc0 = __builtin_amdgcn_mfma_f32_16x16x32_f16(a, bfrag[l][0][ks], acc0, 0, 0, 0);
          acc1 = __builtin_amdgcn_mfma_f32_16x16x32_f16(a, bfrag[l][1][ks], acc1, 0, 0, 0);
        }
#pragma unroll
        for (int ks = 4; ks < 8; ++ks) {
          half8 a = *(const half8*)(Hb + lane15 * STRD + (ks - 4) * 32 + quad * 8);
          acc0 = __builtin_amdgcn_mfma_f32_16x16x32_f16(a, bfrag[l][0][ks], acc0, 0, 0, 0);
          acc1 = __builtin_amdgcn_mfma_f32_16x16x32_f16(a, bfrag[l][1][ks], acc1, 0, 0, 0);
        }
        // --- epilogue: write O[l][pt]; nobody reads that buffer this phase ---
#pragma unroll
        for (int r = 0; r < 4; ++r) {
          int m  = quad * 4 + r;
          int n0 = wid * 32 + lane15;
          int n1 = n0 + 16;
          float v0 = tanh_fast(acc0[r]);
          float v1 = tanh_fast(acc1[r]);
          Ob[m * STRD + n0] = (_Float16)v0;
          Ob[m * STRD + n1] = (_Float16)v1;
          if (g == 0 && l == 4) {  // group boundary -> global (L2-resident)
            _Float16* sp = seq + ((size_t)(b0 + m) * SEQL + t) * HID;
            sp[n0] = (_Float16)v0;
            sp[n1] = (_Float16)v1;
          }
        }
      }
    };
    for (int t2 = 0; t2 < SEQL; t2 += 2) {  // compile-time parity
      step(t2, 0);
      step(t2 + 1, 1);
    }
  }
  __syncthreads();

  // --- FC on layer-9 h at t=27: O(l=4, parity=1) = lds + BUFH*10 ---
  if (tid < BB * NC) {
    int c = tid >> 4;
    int b = tid & 15;
    float acc = fcb[c];
    const float* wr = fcW + c * HID;
    const _Float16* hr = lds + BUFH * 10 + b * STRD;
#pragma unroll 4
    for (int k = 0; k < HID; ++k) acc += (float)hr[k] * wr[k];
    out[(size_t)(b0 + b) * NC + c] = acc;
  }
}

extern "C" void kernel_launch(void* const* d_in, const int* in_sizes, int n_in,
                              void* d_out, int out_size, void* d_ws, size_t ws_size,
                              hipStream_t stream) {
  const float* x    = (const float*)d_in[0];
  const float* Wih0 = (const float*)d_in[1];
  const float* Wih  = (const float*)d_in[2];
  const float* Whh  = (const float*)d_in[3];
  const float* bih  = (const float*)d_in[4];
  const float* bhh  = (const float*)d_in[5];
  const float* fcW  = (const float*)d_in[6];
  const float* fcb  = (const float*)d_in[7];
  float* out = (float*)d_out;

  _Float16* Wcat = (_Float16*)((char*)d_ws + WS_WCAT_OFF);
  float*    bs   = (float*)((char*)d_ws + WS_BIAS_OFF);
  _Float16* seq  = (_Float16*)((char*)d_ws + WS_SEQ_OFF);

  convert_weights<<<dim3(80), dim3(256), 0, stream>>>(Wih0, Wih, Whh, bih, bhh, Wcat, bs);
  rnn_fused<<<dim3(BATCH / BB), dim3(256), 0, stream>>>(x, Wcat, bs, fcW, fcb, seq, out);
}

// Round 3
// 265.881 us; speedup vs baseline: 1.7376x; 1.2205x over previous
//
#include <hip/hip_runtime.h>
#include <cstdint>
#include <cstddef>

#define HID 128
#define SEQL 28
#define INP 28
#define NL 10
#define NC 10
#define BATCH 4096
#define BB 16             // batch rows per block
#define STRD 136          // padded row stride in halfs (272 B, b128-aligned)
#define BUFH (16 * STRD)  // halfs per 16x128 activation buffer

typedef _Float16 half8 __attribute__((ext_vector_type(8)));
typedef float    f32x4 __attribute__((ext_vector_type(4)));

// ---------------- ws layout (bytes) ----------------
// Wcat : [NL][HID][256] f16 : 655360 @ 0   row n: [Wih(128, l0 zero-padded) | Whh(128)]
// bias : [NL][HID] f32      : 5120   @ 655360   (b_ih + b_hh)
// seq  : [BATCH][SEQL][HID] f16 : 29360128 @ 660480 (group 0->1 boundary acts)
#define WS_WCAT_OFF 0
#define WS_BIAS_OFF 655360
#define WS_SEQ_OFF  660480

__global__ void convert_weights(const float* __restrict__ Wih0,
                                const float* __restrict__ Wih,
                                const float* __restrict__ Whh,
                                const float* __restrict__ bih,
                                const float* __restrict__ bhh,
                                _Float16* __restrict__ Wcat,
                                float* __restrict__ bias) {
  int tg = blockIdx.x * blockDim.x + threadIdx.x;
  if (tg >= NL * HID * 16) return;
  int r = tg >> 4, seg = tg & 15;
  int l = r / HID, n = r % HID;
  int k0 = seg * 16;
  _Float16* dst = Wcat + (size_t)r * 256 + k0;
  if (l == 0) {
#pragma unroll
    for (int i = 0; i < 16; ++i) {
      int k = k0 + i;
      float v = 0.f;
      if (k < INP) v = Wih0[n * INP + k];
      else if (k >= HID) v = Whh[(size_t)n * HID + (k - HID)];
      dst[i] = (_Float16)v;
    }
  } else {
    const float* src = (k0 < HID)
        ? (Wih + ((size_t)(l - 1) * HID + n) * HID + k0)
        : (Whh + ((size_t)l * HID + n) * HID + (k0 - HID));
#pragma unroll
    for (int i = 0; i < 16; ++i) dst[i] = (_Float16)src[i];
  }
  if (seg == 0) bias[r] = bih[r] + bhh[r];
}

__device__ __forceinline__ float tanh_fast(float v) {
  float e = __expf(2.f * v);
  return 1.f - 2.f / (e + 1.f);
}

// 512 threads = 8 waves; wave wid owns n-tile [wid*16, wid*16+16).
// LDS: X(p) at lds + BUFH*p (p=0,1); O(l,p) at lds + BUFH*(2 + 2*l + p).
__global__ __launch_bounds__(512, 2) void rnn_fused(
    const float* __restrict__ x,
    const _Float16* __restrict__ Wcat,
    const float* __restrict__ bias,
    const float* __restrict__ fcW,
    const float* __restrict__ fcb,
    _Float16* __restrict__ seq,
    float* __restrict__ out) {
  __shared__ _Float16 lds[BUFH * 12] __attribute__((aligned(16)));

  const int tid    = threadIdx.x;
  const int lane15 = tid & 15;        // MFMA A-row m / D-col n
  const int quad   = (tid >> 4) & 3;  // MFMA quad
  const int wid    = tid >> 6;        // wave id 0..7 -> n-tile
  const int b0     = blockIdx.x * BB;
  const int frow   = tid >> 5;        // fill: 16 rows x 32 segs of 4 halfs
  const int fseg   = tid & 31;

  half8 bfrag[5][8];
  float biasv[5];

  for (int g = 0; g < 2; ++g) {
    // --- stage 5 layers of weights into registers (160 VGPRs) ---
    const _Float16* Wg = Wcat + (size_t)(g * 5) * HID * 256;
    const int n0 = wid * 16 + lane15;
#pragma unroll
    for (int l = 0; l < 5; ++l) {
#pragma unroll
      for (int ks = 0; ks < 8; ++ks)
        bfrag[l][ks] = *(const half8*)(Wg + ((size_t)l * HID + n0) * 256 + ks * 32 + quad * 8);
      biasv[l] = bias[(g * 5 + l) * HID + n0];
    }
    __syncthreads();  // prev group's LDS reads complete before re-zeroing
    {
      uint4 z; z.x = z.y = z.z = z.w = 0u;
      for (int i = tid; i < (BUFH * 10) / 8; i += 512)
        ((uint4*)(lds + 2 * BUFH))[i] = z;
    }

    // input(t) -> registers
    auto load_next = [&](int t, float* pf, uint2* pu) {
      if (g == 0) {
        const float* xb = x + ((size_t)(b0 + frow) * SEQL + t) * INP;
        int c0 = fseg * 4;
#pragma unroll
        for (int i = 0; i < 4; ++i) pf[i] = (c0 + i < INP) ? xb[c0 + i] : 0.f;
      } else {
        *pu = *(const uint2*)(seq + ((size_t)(b0 + frow) * SEQL + t) * HID + fseg * 4);
      }
    };
    // registers -> X panel
    auto store_X = [&](_Float16* Xb, const float* pf, const uint2* pu) {
      _Float16* dst = Xb + frow * STRD + fseg * 4;
      if (g == 0) {
        _Float16 h4[4];
#pragma unroll
        for (int i = 0; i < 4; ++i) h4[i] = (_Float16)pf[i];
        *(uint2*)dst = *(const uint2*)h4;
      } else {
        *(uint2*)dst = *pu;
      }
    };

    // prefill X[0] for t=0 (covered by the t=0,l=0 barrier below)
    {
      float pf[4]; uint2 pu;
      load_next(0, pf, &pu);
      store_X(lds, pf, &pu);
    }

    auto step = [&](int t, int pt) {
      float pf[4]; uint2 pu;
      const bool have_next = (t + 1 < SEQL);
      if (have_next) load_next(t + 1, pf, &pu);  // prefetch next input early
#pragma unroll
      for (int l = 0; l < 5; ++l) {
        __syncthreads();  // inputs of this layer complete; old readers done
        if (l == 2 && have_next) store_X(lds + (1 - pt) * BUFH, pf, &pu);
        const _Float16* INb = (l == 0) ? lds + pt * BUFH
                                       : lds + BUFH * (2 + 2 * (l - 1) + pt);
        const _Float16* Hb  = lds + BUFH * (2 + 2 * l + (1 - pt));
        _Float16*       Ob  = lds + BUFH * (2 + 2 * l + pt);

        f32x4 accA = {biasv[l], biasv[l], biasv[l], biasv[l]};
        f32x4 accB = {0.f, 0.f, 0.f, 0.f};
#pragma unroll
        for (int ks = 0; ks < 4; ++ks) {
          half8 a = *(const half8*)(INb + lane15 * STRD + ks * 32 + quad * 8);
          accA = __builtin_amdgcn_mfma_f32_16x16x32_f16(a, bfrag[l][ks], accA, 0, 0, 0);
        }
#pragma unroll
        for (int ks = 0; ks < 4; ++ks) {
          half8 a = *(const half8*)(Hb + lane15 * STRD + ks * 32 + quad * 8);
          accB = __builtin_amdgcn_mfma_f32_16x16x32_f16(a, bfrag[l][4 + ks], accB, 0, 0, 0);
        }
        // --- epilogue: 4 rows of this wave's n-tile ---
#pragma unroll
        for (int r = 0; r < 4; ++r) {
          int m = quad * 4 + r;
          float v = tanh_fast(accA[r] + accB[r]);
          Ob[m * STRD + n0] = (_Float16)v;
          if (g == 0 && l == 4)
            seq[((size_t)(b0 + m) * SEQL + t) * HID + n0] = (_Float16)v;
        }
      }
    };
    for (int t2 = 0; t2 < SEQL; t2 += 2) {  // compile-time parity
      step(t2, 0);
      step(t2 + 1, 1);
    }
  }
  __syncthreads();

  // --- FC on layer-9 h at t=27 (parity 1): O(4,1) = lds + BUFH*11 ---
  if (tid < BB * NC) {
    int c = tid >> 4;
    int b = tid & 15;
    float acc = fcb[c];
    const float* wr = fcW + c * HID;
    const _Float16* hr = lds + BUFH * 11 + b * STRD;
#pragma unroll 4
    for (int k = 0; k < HID; ++k) acc += (float)hr[k] * wr[k];
    out[(size_t)(b0 + b) * NC + c] = acc;
  }
}

extern "C" void kernel_launch(void* const* d_in, const int* in_sizes, int n_in,
                              void* d_out, int out_size, void* d_ws, size_t ws_size,
                              hipStream_t stream) {
  const float* x    = (const float*)d_in[0];
  const float* Wih0 = (const float*)d_in[1];
  const float* Wih  = (const float*)d_in[2];
  const float* Whh  = (const float*)d_in[3];
  const float* bih  = (const float*)d_in[4];
  const float* bhh  = (const float*)d_in[5];
  const float* fcW  = (const float*)d_in[6];
  const float* fcb  = (const float*)d_in[7];
  float* out = (float*)d_out;

  _Float16* Wcat = (_Float16*)((char*)d_ws + WS_WCAT_OFF);
  float*    bs   = (float*)((char*)d_ws + WS_BIAS_OFF);
  _Float16* seq  = (_Float16*)((char*)d_ws + WS_SEQ_OFF);

  convert_weights<<<dim3(80), dim3(256), 0, stream>>>(Wih0, Wih, Whh, bih, bhh, Wcat, bs);
  rnn_fused<<<dim3(BATCH / BB), dim3(512), 0, stream>>>(x, Wcat, bs, fcW, fcb, seq, out);
}

// Round 4
// 243.301 us; speedup vs baseline: 1.8989x; 1.0928x over previous
//
#include <hip/hip_runtime.h>
#include <cstdint>
#include <cstddef>

#define HID 128
#define SEQL 28
#define INP 28
#define NL 10
#define NC 10
#define BATCH 4096
#define BB 16             // batch rows per block
#define STRD 136          // padded row stride in halfs (272 B, b128-aligned)
#define BUFH (16 * STRD)  // halfs per 16x128 activation buffer

typedef _Float16 half8 __attribute__((ext_vector_type(8)));
typedef float    f32x4 __attribute__((ext_vector_type(4)));

// ---------------- ws layout (bytes) ----------------
// Wcat : [NL][HID][256] f16 : 655360 @ 0   row n: [Wih(128, l0 zero-padded) | Whh(128)]
// bias : [NL][HID] f32      : 5120   @ 655360   (b_ih + b_hh)
// seq  : [BATCH][SEQL][HID] f16 : 29360128 @ 660480 (group 0->1 boundary acts)
#define WS_WCAT_OFF 0
#define WS_BIAS_OFF 655360
#define WS_SEQ_OFF  660480

__global__ void convert_weights(const float* __restrict__ Wih0,
                                const float* __restrict__ Wih,
                                const float* __restrict__ Whh,
                                const float* __restrict__ bih,
                                const float* __restrict__ bhh,
                                _Float16* __restrict__ Wcat,
                                float* __restrict__ bias) {
  int tg = blockIdx.x * blockDim.x + threadIdx.x;
  if (tg >= NL * HID * 16) return;
  int r = tg >> 4, seg = tg & 15;
  int l = r / HID, n = r % HID;
  int k0 = seg * 16;
  _Float16* dst = Wcat + (size_t)r * 256 + k0;
  if (l == 0) {
#pragma unroll
    for (int i = 0; i < 16; ++i) {
      int k = k0 + i;
      float v = 0.f;
      if (k < INP) v = Wih0[n * INP + k];
      else if (k >= HID) v = Whh[(size_t)n * HID + (k - HID)];
      dst[i] = (_Float16)v;
    }
  } else {
    const float* src = (k0 < HID)
        ? (Wih + ((size_t)(l - 1) * HID + n) * HID + k0)
        : (Whh + ((size_t)l * HID + n) * HID + (k0 - HID));
#pragma unroll
    for (int i = 0; i < 16; ++i) dst[i] = (_Float16)src[i];
  }
  if (seg == 0) bias[r] = bih[r] + bhh[r];
}

__device__ __forceinline__ float tanh_fast(float v) {
  float e = __expf(2.f * v);
  return 1.f - 2.f / (e + 1.f);
}

// 512 threads = 8 waves; wave wid owns n-tile [wid*16, wid*16+16) for all layers.
// Diagonal wavefront: at tick tau, cell (l, t=tau-l) for l in [lmin,lmax].
// LDS slots (BUFH halfs each): X(p)=slot p (p=0,1); O(l,p)=slot 2+2l+p.
// Cell (l,t) @ tick tau (pt=tau&1): reads INb = l? O(l-1,1-pt) : X(pt),
// Hb = O(l,1-pt); writes O(l,pt). All intra-tick accesses hazard-free ->
// ONE barrier per tick (64 ticks vs 280 barrier-phases in round 3).
__global__ __launch_bounds__(512, 2) void rnn_fused(
    const float* __restrict__ x,
    const _Float16* __restrict__ Wcat,
    const float* __restrict__ bias,
    const float* __restrict__ fcW,
    const float* __restrict__ fcb,
    _Float16* __restrict__ seq,
    float* __restrict__ out) {
  __shared__ _Float16 lds[BUFH * 12] __attribute__((aligned(16)));

  const int tid    = threadIdx.x;
  const int lane15 = tid & 15;        // MFMA A-row m / D-col n
  const int quad   = (tid >> 4) & 3;  // MFMA quad
  const int wid    = tid >> 6;        // wave id 0..7 -> n-tile
  const int b0     = blockIdx.x * BB;
  const int n0v    = wid * 16 + lane15;
  // g1 fill: 16 rows x 32 segs of 4 halfs (512 threads)
  const int frow1  = tid >> 5;
  const int fseg1  = tid & 31;
  // g0 fill: 16 rows x 8 segs of 4 floats (128 threads)
  const int frow0  = tid >> 3;
  const int fc0    = (tid & 7) * 4;

  half8 bfrag[5][8];
  float biasv[5];

  for (int g = 0; g < 2; ++g) {
    // --- stage 5 layers of weights into registers (160 VGPRs) ---
    const _Float16* Wg = Wcat + (size_t)(g * 5) * HID * 256;
#pragma unroll
    for (int l = 0; l < 5; ++l) {
#pragma unroll
      for (int ks = 0; ks < 8; ++ks)
        bfrag[l][ks] = *(const half8*)(Wg + ((size_t)l * HID + n0v) * 256 + ks * 32 + quad * 8);
      biasv[l] = bias[(g * 5 + l) * HID + n0v];
    }
    __syncthreads();  // prev group's LDS reads complete before re-zeroing
    {
      uint4 z; z.x = z.y = z.z = z.w = 0u;
      for (int i = tid; i < (BUFH * 10) / 8; i += 512)
        ((uint4*)(lds + 2 * BUFH))[i] = z;
    }

    float pfx[4];  // g0 prefetch (f32 x)
    uint2 pfu;     // g1 prefetch (f16 seq)

    auto load_next = [&](int t) {
      if (g == 0) {
        if (tid < 128) {
          const float* xb = x + ((size_t)(b0 + frow0) * SEQL + t) * INP;
#pragma unroll
          for (int i = 0; i < 4; ++i) pfx[i] = (fc0 + i < INP) ? xb[fc0 + i] : 0.f;
        }
      } else {
        pfu = *(const uint2*)(seq + ((size_t)(b0 + frow1) * SEQL + t) * HID + fseg1 * 4);
      }
    };
    auto store_X = [&](int slot) {
      if (g == 0) {
        if (tid < 128) {
          _Float16 h4[4];
#pragma unroll
          for (int i = 0; i < 4; ++i) h4[i] = (_Float16)pfx[i];
          *(uint2*)(lds + slot * BUFH + frow0 * STRD + fc0) = *(const uint2*)h4;
        }
      } else {
        *(uint2*)(lds + slot * BUFH + frow1 * STRD + fseg1 * 4) = pfu;
      }
    };

    // prefill X[0] with t=0 input (visible after tick-0 barrier)
    load_next(0);
    store_X(0);

    auto tick = [&](int tau, int pt, int lmin, int lmax) {
      __syncthreads();
      const bool hn = (tau + 1) < SEQL;
      if (hn) load_next(tau + 1);  // global load issued early, consumed at end
#pragma unroll
      for (int l = lmin; l <= lmax; ++l) {
        const _Float16* INb = (l == 0) ? lds + pt * BUFH
                                       : lds + (2 + 2 * (l - 1) + (1 - pt)) * BUFH;
        const _Float16* Hb  = lds + (2 + 2 * l + (1 - pt)) * BUFH;
        _Float16*       Ob  = lds + (2 + 2 * l + pt) * BUFH;

        f32x4 accA = {biasv[l], biasv[l], biasv[l], biasv[l]};
        f32x4 accB = {0.f, 0.f, 0.f, 0.f};
        const int nkin = (l == 0 && g == 0) ? 1 : 4;  // l0/g0: x only 32 wide
#pragma unroll
        for (int ks = 0; ks < nkin; ++ks) {
          half8 a = *(const half8*)(INb + lane15 * STRD + ks * 32 + quad * 8);
          accA = __builtin_amdgcn_mfma_f32_16x16x32_f16(a, bfrag[l][ks], accA, 0, 0, 0);
        }
#pragma unroll
        for (int ks = 0; ks < 4; ++ks) {
          half8 a = *(const half8*)(Hb + lane15 * STRD + ks * 32 + quad * 8);
          accB = __builtin_amdgcn_mfma_f32_16x16x32_f16(a, bfrag[l][4 + ks], accB, 0, 0, 0);
        }
#pragma unroll
        for (int r = 0; r < 4; ++r) {
          int m = quad * 4 + r;
          float v = tanh_fast(accA[r] + accB[r]);
          Ob[m * STRD + n0v] = (_Float16)v;
          if (g == 0 && l == 4)
            seq[((size_t)(b0 + m) * SEQL + (tau - 4)) * HID + n0v] = (_Float16)v;
        }
      }
      if (hn) store_X(1 - pt);  // X[(tau+1)&1]: nobody reads it this tick
    };

    // head (ragged top of the diagonal)
    tick(0, 0, 0, 0);
    tick(1, 1, 0, 1);
    tick(2, 0, 0, 2);
    tick(3, 1, 0, 3);
    // body: all 5 cells active, branch-free
    for (int tt = 4; tt < 28; tt += 2) {
      tick(tt, 0, 0, 4);
      tick(tt + 1, 1, 0, 4);
    }
    // tail
    tick(28, 0, 1, 4);
    tick(29, 1, 2, 4);
    tick(30, 0, 3, 4);
    tick(31, 1, 4, 4);
  }
  __syncthreads();

  // --- FC on layer-9 h at t=27: written at tick 31 (pt=1) -> O(4,1) = slot 11 ---
  if (tid < BB * NC) {
    int c = tid >> 4;
    int b = tid & 15;
    float acc = fcb[c];
    const float* wr = fcW + c * HID;
    const _Float16* hr = lds + BUFH * 11 + b * STRD;
#pragma unroll 4
    for (int k = 0; k < HID; ++k) acc += (float)hr[k] * wr[k];
    out[(size_t)(b0 + b) * NC + c] = acc;
  }
}

extern "C" void kernel_launch(void* const* d_in, const int* in_sizes, int n_in,
                              void* d_out, int out_size, void* d_ws, size_t ws_size,
                              hipStream_t stream) {
  const float* x    = (const float*)d_in[0];
  const float* Wih0 = (const float*)d_in[1];
  const float* Wih  = (const float*)d_in[2];
  const float* Whh  = (const float*)d_in[3];
  const float* bih  = (const float*)d_in[4];
  const float* bhh  = (const float*)d_in[5];
  const float* fcW  = (const float*)d_in[6];
  const float* fcb  = (const float*)d_in[7];
  float* out = (float*)d_out;

  _Float16* Wcat = (_Float16*)((char*)d_ws + WS_WCAT_OFF);
  float*    bs   = (float*)((char*)d_ws + WS_BIAS_OFF);
  _Float16* seq  = (_Float16*)((char*)d_ws + WS_SEQ_OFF);

  convert_weights<<<dim3(80), dim3(256), 0, stream>>>(Wih0, Wih, Whh, bih, bhh, Wcat, bs);
  rnn_fused<<<dim3(BATCH / BB), dim3(512), 0, stream>>>(x, Wcat, bs, fcW, fcb, seq, out);
}